// Round 12
// baseline (208.158 us; speedup 1.0000x reference)
//
#include <hip/hip_runtime.h>

// ---------------------------------------------------------------------------
// Mamba-2 block (BATCH=2, SEQ=4096, DIM=1024, NH=16, HD=64, BLOCK=64)
//   1) prep: x -> bf16 | wdt -> bf16 (16x1024) | transpose wq/wk/wv/wo -> bf16
//   2) dt = softplus(x_bf @ wdt^T + b)  [MFMA]
//   3) QKV GEMM: proven 128x128 BK=64 XOR-swizzled 2-barrier kernel, with
//      TWO m-tiles per block (grid 768 = single scheduling round, B-panel
//      L2-reused on pass 2). XCD swizzle. RoPE / dt epilogues.
//   4) ssd_states (MFMA): chunk states (bf16) + chunk decay
//   5) scan (prefetch-2): inc states (bf16) + final state -> d_out tail
//   6) ssd_y (MFMA, S from global): Y = (C@B^T . L)@X + (C.sde)@S^T -> bf16 y
//   7) wo GEMM: same 128x128 structure (f32 -> d_out)
// ---------------------------------------------------------------------------

typedef __bf16 bf16x8 __attribute__((ext_vector_type(8)));
typedef float f32x4 __attribute__((ext_vector_type(4)));
typedef unsigned int u32x4 __attribute__((ext_vector_type(4)));
typedef unsigned short u16x8 __attribute__((ext_vector_type(8)));
typedef unsigned short u16x4 __attribute__((ext_vector_type(4)));

__device__ __forceinline__ unsigned short f2bf(float f) {
  unsigned int u = __builtin_bit_cast(unsigned int, f);
  u += 0x7fffu + ((u >> 16) & 1u);  // RNE
  return (unsigned short)(u >> 16);
}
__device__ __forceinline__ float bf2f(unsigned short s) {
  unsigned int u = ((unsigned int)s) << 16;
  return __builtin_bit_cast(float, u);
}

#define GLOAD16(gp, lp)                                                \
  __builtin_amdgcn_global_load_lds(                                    \
      (const __attribute__((address_space(1))) void*)(gp),             \
      (__attribute__((address_space(3))) void*)(lp), 16, 0, 0)

// ---------------- prep: x->bf16 | wdt^T->bf16 | w transpose ----------------
__global__ __launch_bounds__(256) void prep_kernel(
    const float* __restrict__ x, unsigned short* __restrict__ x_bf,
    const float* __restrict__ wdt, unsigned short* __restrict__ wdt_bf,
    const float* __restrict__ w0, const float* __restrict__ w1,
    const float* __restrict__ w2, const float* __restrict__ w3,
    unsigned short* __restrict__ wt) {
  const int bx = blockIdx.x;
  const int tid = threadIdx.x;
  if (bx < 8192) {
    const int g = bx * 256 + tid;
    f32x4 v = *reinterpret_cast<const f32x4*>(x + (size_t)g * 4);
    u16x4 o;
    o.x = f2bf(v.x); o.y = f2bf(v.y); o.z = f2bf(v.z); o.w = f2bf(v.w);
    *reinterpret_cast<u16x4*>(x_bf + (size_t)g * 4) = o;
  } else if (bx < 8256) {
    const int g = (bx - 8192) * 256 + tid;  // 0..16383
    const int n = g >> 10, k = g & 1023;
    wdt_bf[g] = f2bf(wdt[k * 16 + n]);
  } else {
    __shared__ float tile[32][33];
    const int t = bx - 8256;  // 0..4095
    const int z = t >> 10, by = (t >> 5) & 31, bxx = t & 31;
    const float* w = (z == 0) ? w0 : (z == 1) ? w1 : (z == 2) ? w2 : w3;
    unsigned short* o = wt + (size_t)z * 1024 * 1024;
    const int tx = tid & 31, ty = tid >> 5;  // (32,8)
#pragma unroll
    for (int i = 0; i < 4; ++i)
      tile[ty + i * 8][tx] = w[(size_t)(by * 32 + ty + i * 8) * 1024 + bxx * 32 + tx];
    __syncthreads();
#pragma unroll
    for (int i = 0; i < 4; ++i)
      o[(size_t)(bxx * 32 + ty + i * 8) * 1024 + by * 32 + tx] =
          f2bf(tile[tx][ty + i * 8]);
  }
}

// ---------------- dt = softplus(x_bf @ wdt_t^T + b)  [MFMA, M-tile 32] ------
__global__ __launch_bounds__(128) void dt_gemm_kernel(
    const unsigned short* __restrict__ A,   // 8192x1024 bf16
    const unsigned short* __restrict__ Bt,  // 16x1024 bf16
    const float* __restrict__ bdt, float* __restrict__ dt) {
  __shared__ unsigned short As[2 * 1024];  // [wave][kk][16][32]
  const int tid = threadIdx.x, lane = tid & 63, w = tid >> 6;  // w in {0,1}
  const int m0 = blockIdx.x * 32;
  const unsigned short* ga =
      A + (size_t)(m0 + w * 16 + (lane >> 2)) * 1024 + (lane & 3) * 8;
  unsigned short* la = As + w * 1024;  // wave-uniform base (elements)
  const int lr = lane & 15, lk = (lane >> 4) * 8;
  const unsigned short* gb = Bt + (size_t)lr * 1024 + lk;
  f32x4 acc = {};
  for (int kt = 0; kt < 1024; kt += 64) {
    GLOAD16(ga + kt, la);                 // k-half 0
    GLOAD16(ga + kt + 32, la + 512);      // k-half 1
    bf16x8 bF0 = *reinterpret_cast<const bf16x8*>(gb + kt);
    bf16x8 bF1 = *reinterpret_cast<const bf16x8*>(gb + kt + 32);
    __syncthreads();
    bf16x8 aF0 = *reinterpret_cast<const bf16x8*>(&la[lr * 32 + lk]);
    bf16x8 aF1 = *reinterpret_cast<const bf16x8*>(&la[512 + lr * 32 + lk]);
    acc = __builtin_amdgcn_mfma_f32_16x16x32_bf16(aF0, bF0, acc, 0, 0, 0);
    acc = __builtin_amdgcn_mfma_f32_16x16x32_bf16(aF1, bF1, acc, 0, 0, 0);
    __syncthreads();
  }
  const int h = lr;  // C/D: col = lane&15
  const float bv = bdt[h];
#pragma unroll
  for (int r = 0; r < 4; ++r) {
    const int row = m0 + w * 16 + (lane >> 4) * 4 + r;
    const float a = acc[r] + bv;
    const float sp = (a > 0.f) ? (a + log1pf(expf(-a))) : log1pf(expf(a));
    dt[(size_t)row * 16 + h] = sp;
  }
}

// ---------------- QKV: 128x128 BK=64 swizzled, 2 m-tiles per block ----------
// Grid (24,32): 768 blocks = one full scheduling round at 4 blocks/CU.
// Pass p computes rows mb + p*128 over the same n0 -> B-panel L2-hot on p=1.
// Inner K-loop is the proven R5/R8/R10 structure (0 bank conflicts).
__global__ __launch_bounds__(256) void gemm128_qkv_kernel(
    const unsigned short* __restrict__ A, const unsigned short* __restrict__ Bt,
    unsigned short* __restrict__ oq, unsigned short* __restrict__ ok,
    unsigned short* __restrict__ ov, const float* __restrict__ cosb,
    const float* __restrict__ sinb, const float* __restrict__ dtb) {
  __shared__ unsigned short As[128 * 64];
  __shared__ unsigned short Bs[128 * 64];
  const int tid = threadIdx.x, lane = tid & 63, w = tid >> 6;
  // XCD swizzle over 768 blocks (divisible by 8)
  const int id = blockIdx.x + gridDim.x * blockIdx.y;
  const int cpx = (gridDim.x * gridDim.y) >> 3;
  const int swz = (id & 7) * cpx + (id >> 3);
  const int mb = (swz / gridDim.x) * 256, n0 = (swz % gridDim.x) * 128;
  const int rw = lane >> 3;                      // row & 7
  const int cu = ((lane & 7) ^ rw) * 8;          // swizzled source col (elements)
  const unsigned short* gb = Bt + (size_t)(n0 + w * 8 + rw) * 1024 + cu;
  unsigned short* la = As + (w * 8) * 64;        // wave-uniform LDS base
  unsigned short* lb = Bs + (w * 8) * 64;
  const int lr = lane & 15, lku = lane >> 4;
  const int wr = w >> 1, wc = w & 1;
  const int xr = lr & 7;

  for (int pass = 0; pass < 2; ++pass) {
    const int m0 = mb + pass * 128;
    const unsigned short* ga = A + (size_t)(m0 + w * 8 + rw) * 1024 + cu;
    f32x4 acc[4][4] = {};
    for (int kt = 0; kt < 1024; kt += 64) {
#pragma unroll
      for (int g = 0; g < 4; ++g) {
        GLOAD16(ga + kt + (size_t)(g * 32) * 1024, la + g * 32 * 64);
        GLOAD16(gb + kt + (size_t)(g * 32) * 1024, lb + g * 32 * 64);
      }
      __syncthreads();
#pragma unroll
      for (int kk = 0; kk < 2; ++kk) {  // k-halves of 32
        const int un = (((kk * 4 + lku) ^ xr) * 8);  // swizzled 16B unit
        bf16x8 aF[4], bF[4];
#pragma unroll
        for (int i = 0; i < 4; ++i) {
          aF[i] = *reinterpret_cast<const bf16x8*>(&As[(wr * 64 + i * 16 + lr) * 64 + un]);
          bF[i] = *reinterpret_cast<const bf16x8*>(&Bs[(wc * 64 + i * 16 + lr) * 64 + un]);
        }
#pragma unroll
        for (int i = 0; i < 4; ++i)
#pragma unroll
          for (int j = 0; j < 4; ++j)
            acc[i][j] = __builtin_amdgcn_mfma_f32_16x16x32_bf16(aF[i], bF[j], acc[i][j], 0, 0, 0);
      }
      __syncthreads();  // also guards next pass's first stage
    }
    // ---- epilogue (registers only; LDS free for next pass) ----
    const int r0 = m0 + wr * 64 + ((lane >> 4) << 2);
    const int col = n0 + wc * 64;  // 64-aligned, 0..3008
    if (col < 2048) {
      // RoPE epilogue -> q_bf or k_bf
      unsigned short* O = (col < 1024) ? oq : ok;
      const int cbase = col & 1023;
#pragma unroll
      for (int i = 0; i < 4; ++i)
#pragma unroll
        for (int jj = 0; jj < 2; ++jj) {
          const int d1 = jj * 16 + lr;  // 0..31; cos[d]==cos[d+32]
#pragma unroll
          for (int r = 0; r < 4; ++r) {
            const int row = r0 + i * 16 + r;
            const int l = row & 4095;
            const float cv = cosb[(size_t)l * 64 + d1];
            const float sv = sinb[(size_t)l * 64 + d1];
            const float v1 = acc[i][jj][r], v2 = acc[i][jj + 2][r];
            O[(size_t)row * 1024 + cbase + d1] = f2bf(v1 * cv - v2 * sv);
            O[(size_t)row * 1024 + cbase + d1 + 32] = f2bf(v2 * cv + v1 * sv);
          }
        }
    } else {
      // dt-scale epilogue -> xv_bf
      const int cbase = col - 2048;
      const int h = cbase >> 6;
#pragma unroll
      for (int i = 0; i < 4; ++i)
#pragma unroll
        for (int r = 0; r < 4; ++r) {
          const int row = r0 + i * 16 + r;
          const float dtv = dtb[(size_t)row * 16 + h];
#pragma unroll
          for (int j = 0; j < 4; ++j)
            ov[(size_t)row * 1024 + cbase + j * 16 + lr] = f2bf(acc[i][j][r] * dtv);
        }
    }
  }
}

// ---------------- wo GEMM: proven 128x128 BK=64 swizzled ----------------
__global__ __launch_bounds__(256) void gemm128_wo_kernel(
    const unsigned short* __restrict__ A, const unsigned short* __restrict__ Bt,
    float* __restrict__ O) {
  __shared__ unsigned short As[128 * 64];
  __shared__ unsigned short Bs[128 * 64];
  const int tid = threadIdx.x, lane = tid & 63, w = tid >> 6;
  const int id = blockIdx.x + gridDim.x * blockIdx.y;
  const int cpx = (gridDim.x * gridDim.y) >> 3;
  const int swz = (id & 7) * cpx + (id >> 3);
  const int m0 = (swz / gridDim.x) * 128, n0 = (swz % gridDim.x) * 128;
  const int rw = lane >> 3;
  const int cu = ((lane & 7) ^ rw) * 8;
  const unsigned short* ga = A + (size_t)(m0 + w * 8 + rw) * 1024 + cu;
  const unsigned short* gb = Bt + (size_t)(n0 + w * 8 + rw) * 1024 + cu;
  unsigned short* la = As + (w * 8) * 64;
  unsigned short* lb = Bs + (w * 8) * 64;
  const int lr = lane & 15, lku = lane >> 4;
  const int wr = w >> 1, wc = w & 1;
  const int xr = lr & 7;
  f32x4 acc[4][4] = {};
  for (int kt = 0; kt < 1024; kt += 64) {
#pragma unroll
    for (int g = 0; g < 4; ++g) {
      GLOAD16(ga + kt + (size_t)(g * 32) * 1024, la + g * 32 * 64);
      GLOAD16(gb + kt + (size_t)(g * 32) * 1024, lb + g * 32 * 64);
    }
    __syncthreads();
#pragma unroll
    for (int kk = 0; kk < 2; ++kk) {
      const int un = (((kk * 4 + lku) ^ xr) * 8);
      bf16x8 aF[4], bF[4];
#pragma unroll
      for (int i = 0; i < 4; ++i) {
        aF[i] = *reinterpret_cast<const bf16x8*>(&As[(wr * 64 + i * 16 + lr) * 64 + un]);
        bF[i] = *reinterpret_cast<const bf16x8*>(&Bs[(wc * 64 + i * 16 + lr) * 64 + un]);
      }
#pragma unroll
      for (int i = 0; i < 4; ++i)
#pragma unroll
        for (int j = 0; j < 4; ++j)
          acc[i][j] = __builtin_amdgcn_mfma_f32_16x16x32_bf16(aF[i], bF[j], acc[i][j], 0, 0, 0);
    }
    __syncthreads();
  }
  const int r0 = m0 + wr * 64 + ((lane >> 4) << 2);
  const int c0 = n0 + wc * 64 + lr;
#pragma unroll
  for (int i = 0; i < 4; ++i)
#pragma unroll
    for (int j = 0; j < 4; ++j)
#pragma unroll
      for (int r = 0; r < 4; ++r)
        O[(size_t)(r0 + i * 16 + r) * 1024 + c0 + j * 16] = acc[i][j][r];
}

// ---------------- SSD pre-scan: chunk states (MFMA, bf16 out) ----------------
__global__ __launch_bounds__(256) void ssd_states_kernel(
    const unsigned short* __restrict__ Kb, const unsigned short* __restrict__ Xb,
    const float* __restrict__ dtb, const float* __restrict__ A_log,
    unsigned short* __restrict__ chunk_states, float* __restrict__ chunk_dec) {
  __shared__ unsigned short T1[64 * 72], T2[64 * 72];   // B, X row-major
  __shared__ unsigned short BtL[64 * 72], XdL[64 * 72]; // transposed (k = s)
  __shared__ float csL[64], decL[64];
  const int c = blockIdx.x, h = blockIdx.y, b = blockIdx.z;
  const int tid = threadIdx.x, lane = tid & 63, w = tid >> 6;
  const size_t gbase = ((size_t)(b * 4096 + c * 64)) * 1024 + h * 64;
  {
    const int s = tid >> 2, e0 = (tid & 3) * 16;
    const unsigned short* gk = Kb + gbase + (size_t)s * 1024 + e0;
    const unsigned short* gx = Xb + gbase + (size_t)s * 1024 + e0;
    *(u32x4*)&T1[s * 72 + e0] = *(const u32x4*)gk;
    *(u32x4*)&T1[s * 72 + e0 + 8] = *(const u32x4*)(gk + 8);
    *(u32x4*)&T2[s * 72 + e0] = *(const u32x4*)gx;
    *(u32x4*)&T2[s * 72 + e0 + 8] = *(const u32x4*)(gx + 8);
  }
  if (w == 0) {
    float a = -expf(A_log[h]) * dtb[((size_t)(b * 4096 + c * 64 + lane)) * 16 + h];
    float v = a;
#pragma unroll
    for (int d = 1; d < 64; d <<= 1) {
      float o = __shfl_up(v, d, 64);
      if (lane >= d) v += o;
    }
    const float tot = __shfl(v, 63, 64);
    csL[lane] = v;
    decL[lane] = expf(tot - v);
    if (lane == 0) chunk_dec[((size_t)(b * 16 + h)) * 64 + c] = expf(tot);
  }
  __syncthreads();
#pragma unroll
  for (int q = 0; q < 2; ++q) {  // transpose with dec fold-in
    const int p = lane;
    const int s0 = (q * 4 + w) * 8;
    u16x8 vb, vx;
#pragma unroll
    for (int j = 0; j < 8; ++j) {
      vb[j] = T1[(s0 + j) * 72 + p];
      vx[j] = f2bf(bf2f(T2[(s0 + j) * 72 + p]) * decL[s0 + j]);
    }
    *(u16x8*)&BtL[p * 72 + s0] = vb;
    *(u16x8*)&XdL[p * 72 + s0] = vx;
  }
  __syncthreads();
  const int lr = lane & 15, lk = (lane >> 4) * 8;
  f32x4 acc[4] = {};
#pragma unroll
  for (int kt = 0; kt < 64; kt += 32) {
    bf16x8 aF = *reinterpret_cast<const bf16x8*>(&XdL[(w * 16 + lr) * 72 + kt + lk]);
#pragma unroll
    for (int j = 0; j < 4; ++j) {
      bf16x8 bF = *reinterpret_cast<const bf16x8*>(&BtL[(j * 16 + lr) * 72 + kt + lk]);
      acc[j] = __builtin_amdgcn_mfma_f32_16x16x32_bf16(aF, bF, acc[j], 0, 0, 0);
    }
  }
  const size_t stb = ((size_t)((b * 64 + c) * 16 + h)) * 4096;
#pragma unroll
  for (int j = 0; j < 4; ++j)
#pragma unroll
    for (int r = 0; r < 4; ++r)
      chunk_states[stb + (size_t)(w * 16 + (lane >> 4) * 4 + r) * 64 + j * 16 + lr] =
          f2bf(acc[j][r]);
}

// ---------------- inter-chunk scan (prefetch depth 2) ----------------
__global__ __launch_bounds__(256) void scan_kernel(
    const unsigned short* __restrict__ chunk_states, const float* __restrict__ chunk_dec,
    unsigned short* __restrict__ inc_bf, float* __restrict__ state_out) {
  __shared__ float decs[64];
  const int g = blockIdx.x * 256 + threadIdx.x;
  const int n = g & 63, p = (g >> 6) & 63, h = (g >> 12) & 15, b = g >> 16;
  if (threadIdx.x < 64)
    decs[threadIdx.x] = chunk_dec[(size_t)((blockIdx.x * 256) >> 12 & 15) * 64 +
                                  (size_t)(blockIdx.x >> 8) * 1024 + threadIdx.x];
  __syncthreads();
  const size_t pn = (size_t)p * 64 + n;
  const size_t stride = (size_t)16 * 4096;
  const size_t base0 = ((size_t)(b * 64) * 16 + h) * 4096 + pn;
  float inc = 0.f;
  float cur0 = bf2f(chunk_states[base0]);
  float cur1 = bf2f(chunk_states[base0 + stride]);
  for (int c = 0; c < 64; ++c) {
    const size_t idx = base0 + (size_t)c * stride;
    inc_bf[idx] = f2bf(inc);
    float nxt = (c < 62) ? bf2f(chunk_states[idx + 2 * stride]) : 0.f;
    inc = decs[c] * inc + cur0;
    cur0 = cur1;
    cur1 = nxt;
  }
  state_out[((size_t)(b * 16 + h) * 64 + p) * 64 + n] = inc;
}

// ---------------- SSD post-scan: Y = Gm@X + (C.sde)@S^T (MFMA) ----------------
__global__ __launch_bounds__(256) void ssd_y_kernel(
    const unsigned short* __restrict__ Qb, const unsigned short* __restrict__ Kb,
    const unsigned short* __restrict__ Xb, const unsigned short* __restrict__ Sg,
    const float* __restrict__ dtb, const float* __restrict__ A_log,
    unsigned short* __restrict__ y_bf) {
  __shared__ unsigned short Cb[64 * 72], Bb[64 * 72];
  __shared__ unsigned short Xt[64 * 72], TG[64 * 72];  // TG: X rm, then Gm
  __shared__ float csL[64], sdeL[64];
  const int c = blockIdx.x, h = blockIdx.y, b = blockIdx.z;
  const int tid = threadIdx.x, lane = tid & 63, w = tid >> 6;
  const size_t gbase = ((size_t)(b * 4096 + c * 64)) * 1024 + h * 64;
  const size_t sbase = ((size_t)((b * 64 + c) * 16 + h)) * 4096;
  const unsigned short* gS = Sg + sbase;  // [p][n] bf16, L2-hot
  {
    const int s = tid >> 2, e0 = (tid & 3) * 16;
    const unsigned short* gq = Qb + gbase + (size_t)s * 1024 + e0;
    const unsigned short* gk = Kb + gbase + (size_t)s * 1024 + e0;
    const unsigned short* gx = Xb + gbase + (size_t)s * 1024 + e0;
    *(u32x4*)&Cb[s * 72 + e0] = *(const u32x4*)gq;
    *(u32x4*)&Cb[s * 72 + e0 + 8] = *(const u32x4*)(gq + 8);
    *(u32x4*)&Bb[s * 72 + e0] = *(const u32x4*)gk;
    *(u32x4*)&Bb[s * 72 + e0 + 8] = *(const u32x4*)(gk + 8);
    *(u32x4*)&TG[s * 72 + e0] = *(const u32x4*)gx;
    *(u32x4*)&TG[s * 72 + e0 + 8] = *(const u32x4*)(gx + 8);
  }
  if (w == 0) {
    float a = -expf(A_log[h]) * dtb[((size_t)(b * 4096 + c * 64 + lane)) * 16 + h];
    float v = a;
#pragma unroll
    for (int d = 1; d < 64; d <<= 1) {
      float o = __shfl_up(v, d, 64);
      if (lane >= d) v += o;
    }
    csL[lane] = v;
    sdeL[lane] = expf(v);
  }
  __syncthreads();
  const int lr = lane & 15, lk = (lane >> 4) * 8;
  // G = C @ B^T (contract n)
  f32x4 g[4] = {};
#pragma unroll
  for (int kt = 0; kt < 64; kt += 32) {
    bf16x8 aF = *reinterpret_cast<const bf16x8*>(&Cb[(w * 16 + lr) * 72 + kt + lk]);
#pragma unroll
    for (int j = 0; j < 4; ++j) {
      bf16x8 bF = *reinterpret_cast<const bf16x8*>(&Bb[(j * 16 + lr) * 72 + kt + lk]);
      g[j] = __builtin_amdgcn_mfma_f32_16x16x32_bf16(aF, bF, g[j], 0, 0, 0);
    }
  }
  // transpose X: TG -> Xt
#pragma unroll
  for (int q = 0; q < 2; ++q) {
    const int p = lane;
    const int s0 = (q * 4 + w) * 8;
    u16x8 vx;
#pragma unroll
    for (int j = 0; j < 8; ++j) vx[j] = TG[(s0 + j) * 72 + p];
    *(u16x8*)&Xt[p * 72 + s0] = vx;
  }
  __syncthreads();
  // Gm = (G o L) -> TG ;  Cb *= sde[l]
#pragma unroll
  for (int j = 0; j < 4; ++j)
#pragma unroll
    for (int r = 0; r < 4; ++r) {
      const int l = w * 16 + (lane >> 4) * 4 + r;
      const int s = j * 16 + lr;
      const float gm = (l >= s) ? g[j][r] * expf(csL[l] - csL[s]) : 0.f;
      TG[l * 72 + s] = f2bf(gm);
    }
  {
    const int rl = tid >> 2, e0 = (tid & 3) * 16;
    const float sde = sdeL[rl];
#pragma unroll
    for (int half = 0; half < 2; ++half) {
      u16x8 v = *(u16x8*)&Cb[rl * 72 + e0 + half * 8];
#pragma unroll
      for (int j = 0; j < 8; ++j) v[j] = f2bf(bf2f(v[j]) * sde);
      *(u16x8*)&Cb[rl * 72 + e0 + half * 8] = v;
    }
  }
  __syncthreads();
  // Y = Gm @ Xt^T + Csde @ S^T  (S fragments straight from global/L2)
  f32x4 acc[4] = {};
#pragma unroll
  for (int kt = 0; kt < 64; kt += 32) {
    bf16x8 aG = *reinterpret_cast<const bf16x8*>(&TG[(w * 16 + lr) * 72 + kt + lk]);
    bf16x8 aC = *reinterpret_cast<const bf16x8*>(&Cb[(w * 16 + lr) * 72 + kt + lk]);
#pragma unroll
    for (int j = 0; j < 4; ++j) {
      bf16x8 bX = *reinterpret_cast<const bf16x8*>(&Xt[(j * 16 + lr) * 72 + kt + lk]);
      bf16x8 bS = *reinterpret_cast<const bf16x8*>(gS + (size_t)(j * 16 + lr) * 64 + kt + lk);
      acc[j] = __builtin_amdgcn_mfma_f32_16x16x32_bf16(aG, bX, acc[j], 0, 0, 0);
      acc[j] = __builtin_amdgcn_mfma_f32_16x16x32_bf16(aC, bS, acc[j], 0, 0, 0);
    }
  }
  // scrambled store: row = b*4096 + h*256 + c*4 + (l>>4), col = (l&15)*64 + p
  const size_t orow = (size_t)b * 4096 + h * 256 + c * 4 + w;
#pragma unroll
  for (int j = 0; j < 4; ++j)
#pragma unroll
    for (int r = 0; r < 4; ++r) {
      const int li = (lane >> 4) * 4 + r;
      y_bf[orow * 1024 + li * 64 + j * 16 + lr] = f2bf(acc[j][r]);
    }
}

// ---------------------------------------------------------------------------
extern "C" void kernel_launch(void* const* d_in, const int* in_sizes, int n_in,
                              void* d_out, int out_size, void* d_ws, size_t ws_size,
                              hipStream_t stream) {
  (void)in_sizes; (void)n_in; (void)out_size; (void)ws_size;
  const float* x = (const float*)d_in[0];
  const float* cosb = (const float*)d_in[1];
  const float* sinb = (const float*)d_in[2];
  const float* wq = (const float*)d_in[3];
  const float* wk = (const float*)d_in[4];
  const float* wv = (const float*)d_in[5];
  const float* wo = (const float*)d_in[6];
  const float* A_log = (const float*)d_in[7];
  const float* wdt = (const float*)d_in[8];
  const float* bdt = (const float*)d_in[9];

  float* out_y = (float*)d_out;        // (2,4096,1024) f32
  float* out_state = out_y + 8388608;  // (2,16,64,64) f32

  const size_t MBB = 1048576;
  char* ws = (char*)d_ws;
  unsigned short* x_bf = (unsigned short*)(ws);              // 16MB, reused as y_bf
  unsigned short* w_t = (unsigned short*)(ws + 16 * MBB);    // 8MB (q,k,v,o transposed)
  unsigned short* q_bf = (unsigned short*)(ws + 24 * MBB);   // 16MB
  unsigned short* k_bf = (unsigned short*)(ws + 40 * MBB);   // 16MB
  unsigned short* xv_bf = (unsigned short*)(ws + 56 * MBB);  // 16MB
  float* dtb = (float*)(ws + 72 * MBB);                      // 0.5MB
  unsigned short* wdt_bf = (unsigned short*)(ws + 73 * MBB); // 32KB
  unsigned short* chunk_states = (unsigned short*)(ws + 74 * MBB);  // 16MB bf16
  float* chunk_dec = (float*)(ws + 90 * MBB);                // 8KB
  unsigned short* inc_bf = (unsigned short*)(ws + 91 * MBB); // 16MB

  prep_kernel<<<12352, 256, 0, stream>>>(x, x_bf, wdt, wdt_bf, wq, wk, wv, wo, w_t);
  dt_gemm_kernel<<<256, 128, 0, stream>>>(x_bf, wdt_bf, bdt, dtb);

  // fused QKV GEMM: N = 3072, grid 24x32, 2 m-tiles per block (768 blocks)
  gemm128_qkv_kernel<<<dim3(24, 32), 256, 0, stream>>>(
      x_bf, w_t, q_bf, k_bf, xv_bf, cosb, sinb, dtb);

  ssd_states_kernel<<<dim3(64, 16, 2), 256, 0, stream>>>(k_bf, xv_bf, dtb, A_log,
                                                         chunk_states, chunk_dec);
  scan_kernel<<<512, 256, 0, stream>>>(chunk_states, chunk_dec, inc_bf, out_state);
  ssd_y_kernel<<<dim3(64, 16, 2), 256, 0, stream>>>(q_bf, k_bf, xv_bf, inc_bf, dtb, A_log,
                                                    x_bf /*y_bf*/);

  gemm128_wo_kernel<<<dim3(8, 64), 256, 0, stream>>>(x_bf /*y_bf*/, w_t + 3 * MBB, out_y);
}

// Round 13
// 159.651 us; speedup vs baseline: 1.3038x; 1.3038x over previous
//
#include <hip/hip_runtime.h>

// ---------------------------------------------------------------------------
// Mamba-2 block (BATCH=2, SEQ=4096, DIM=1024, NH=16, HD=64, BLOCK=64)
// FINAL (= R10 verified-best config, 159.95 us):
//   1) prep: x -> bf16 | wdt -> bf16 (16x1024) | transpose wq/wk/wv/wo -> bf16
//   2) dt = softplus(x_bf @ wdt^T + b)  [MFMA]
//   3) fused QKV GEMM (N=3072): 128x128, BK=64, XOR-swizzled LDS (0 bank
//      conflicts), XCD-aware block swizzle, plain __launch_bounds__(256)
//      (R9 lesson: min-wave cap spills acc -> 487MB scratch). RoPE/dt epi.
//   4) ssd_states (MFMA): chunk states (bf16) + chunk decay
//   5) scan (prefetch-2): inc states (bf16) + final state -> d_out tail
//   6) ssd_y (MFMA, S from global): Y = (C@B^T . L)@X + (C.sde)@S^T -> bf16 y
//   7) wo GEMM: same 128x128 structure (f32 -> d_out)
// ---------------------------------------------------------------------------

typedef __bf16 bf16x8 __attribute__((ext_vector_type(8)));
typedef float f32x4 __attribute__((ext_vector_type(4)));
typedef unsigned int u32x4 __attribute__((ext_vector_type(4)));
typedef unsigned short u16x8 __attribute__((ext_vector_type(8)));
typedef unsigned short u16x4 __attribute__((ext_vector_type(4)));

__device__ __forceinline__ unsigned short f2bf(float f) {
  unsigned int u = __builtin_bit_cast(unsigned int, f);
  u += 0x7fffu + ((u >> 16) & 1u);  // RNE
  return (unsigned short)(u >> 16);
}
__device__ __forceinline__ float bf2f(unsigned short s) {
  unsigned int u = ((unsigned int)s) << 16;
  return __builtin_bit_cast(float, u);
}

#define GLOAD16(gp, lp)                                                \
  __builtin_amdgcn_global_load_lds(                                    \
      (const __attribute__((address_space(1))) void*)(gp),             \
      (__attribute__((address_space(3))) void*)(lp), 16, 0, 0)

// ---------------- prep: x->bf16 | wdt^T->bf16 | w transpose ----------------
__global__ __launch_bounds__(256) void prep_kernel(
    const float* __restrict__ x, unsigned short* __restrict__ x_bf,
    const float* __restrict__ wdt, unsigned short* __restrict__ wdt_bf,
    const float* __restrict__ w0, const float* __restrict__ w1,
    const float* __restrict__ w2, const float* __restrict__ w3,
    unsigned short* __restrict__ wt) {
  const int bx = blockIdx.x;
  const int tid = threadIdx.x;
  if (bx < 8192) {
    const int g = bx * 256 + tid;
    f32x4 v = *reinterpret_cast<const f32x4*>(x + (size_t)g * 4);
    u16x4 o;
    o.x = f2bf(v.x); o.y = f2bf(v.y); o.z = f2bf(v.z); o.w = f2bf(v.w);
    *reinterpret_cast<u16x4*>(x_bf + (size_t)g * 4) = o;
  } else if (bx < 8256) {
    const int g = (bx - 8192) * 256 + tid;  // 0..16383
    const int n = g >> 10, k = g & 1023;
    wdt_bf[g] = f2bf(wdt[k * 16 + n]);
  } else {
    __shared__ float tile[32][33];
    const int t = bx - 8256;  // 0..4095
    const int z = t >> 10, by = (t >> 5) & 31, bxx = t & 31;
    const float* w = (z == 0) ? w0 : (z == 1) ? w1 : (z == 2) ? w2 : w3;
    unsigned short* o = wt + (size_t)z * 1024 * 1024;
    const int tx = tid & 31, ty = tid >> 5;  // (32,8)
#pragma unroll
    for (int i = 0; i < 4; ++i)
      tile[ty + i * 8][tx] = w[(size_t)(by * 32 + ty + i * 8) * 1024 + bxx * 32 + tx];
    __syncthreads();
#pragma unroll
    for (int i = 0; i < 4; ++i)
      o[(size_t)(bxx * 32 + ty + i * 8) * 1024 + by * 32 + tx] =
          f2bf(tile[tx][ty + i * 8]);
  }
}

// ---------------- dt = softplus(x_bf @ wdt_t^T + b)  [MFMA, M-tile 32] ------
__global__ __launch_bounds__(128) void dt_gemm_kernel(
    const unsigned short* __restrict__ A,   // 8192x1024 bf16
    const unsigned short* __restrict__ Bt,  // 16x1024 bf16
    const float* __restrict__ bdt, float* __restrict__ dt) {
  __shared__ unsigned short As[2 * 1024];  // [wave][kk][16][32]
  const int tid = threadIdx.x, lane = tid & 63, w = tid >> 6;  // w in {0,1}
  const int m0 = blockIdx.x * 32;
  const unsigned short* ga =
      A + (size_t)(m0 + w * 16 + (lane >> 2)) * 1024 + (lane & 3) * 8;
  unsigned short* la = As + w * 1024;  // wave-uniform base (elements)
  const int lr = lane & 15, lk = (lane >> 4) * 8;
  const unsigned short* gb = Bt + (size_t)lr * 1024 + lk;
  f32x4 acc = {};
  for (int kt = 0; kt < 1024; kt += 64) {
    GLOAD16(ga + kt, la);                 // k-half 0
    GLOAD16(ga + kt + 32, la + 512);      // k-half 1
    bf16x8 bF0 = *reinterpret_cast<const bf16x8*>(gb + kt);
    bf16x8 bF1 = *reinterpret_cast<const bf16x8*>(gb + kt + 32);
    __syncthreads();
    bf16x8 aF0 = *reinterpret_cast<const bf16x8*>(&la[lr * 32 + lk]);
    bf16x8 aF1 = *reinterpret_cast<const bf16x8*>(&la[512 + lr * 32 + lk]);
    acc = __builtin_amdgcn_mfma_f32_16x16x32_bf16(aF0, bF0, acc, 0, 0, 0);
    acc = __builtin_amdgcn_mfma_f32_16x16x32_bf16(aF1, bF1, acc, 0, 0, 0);
    __syncthreads();
  }
  const int h = lr;  // C/D: col = lane&15
  const float bv = bdt[h];
#pragma unroll
  for (int r = 0; r < 4; ++r) {
    const int row = m0 + w * 16 + (lane >> 4) * 4 + r;
    const float a = acc[r] + bv;
    const float sp = (a > 0.f) ? (a + log1pf(expf(-a))) : log1pf(expf(a));
    dt[(size_t)row * 16 + h] = sp;
  }
}

// ---------------- BK=64 XOR-swizzled bf16 GEMM (proven R5/R8/R10) -----------
// LDS tile [128][64] bf16 (128B rows). Swizzle: LDS(r,u) holds global(r, u^(r&7)),
// u = 16B unit. global_load_lds linear-dest; source col-unit pre-XOR'd;
// ds_read applies the same XOR. Verified 0 bank conflicts.
// Plain __launch_bounds__(256): VGPR 108, no spills.
// XCD-aware block swizzle (grid totals divisible by 8).
// EPI 0: plain f32 out (out = y @ wo).  EPI 3: fused QKV epilogue.
template <int EPI>
__global__ __launch_bounds__(256) void gemm128_kernel(
    const unsigned short* __restrict__ A, const unsigned short* __restrict__ Bt,
    void* __restrict__ out0, unsigned short* __restrict__ out1,
    unsigned short* __restrict__ out2, const float* __restrict__ cosb,
    const float* __restrict__ sinb, const float* __restrict__ dtb) {
  __shared__ unsigned short As[128 * 64];
  __shared__ unsigned short Bs[128 * 64];
  const int tid = threadIdx.x, lane = tid & 63, w = tid >> 6;
  // XCD swizzle: consecutive swizzled ids share A-panels within one XCD's L2
  const int id = blockIdx.x + gridDim.x * blockIdx.y;
  const int cpx = (gridDim.x * gridDim.y) >> 3;
  const int swz = (id & 7) * cpx + (id >> 3);
  const int m0 = (swz / gridDim.x) * 128, n0 = (swz % gridDim.x) * 128;
  const int rw = lane >> 3;                      // row & 7
  const int cu = ((lane & 7) ^ rw) * 8;          // swizzled source col (elements)
  const unsigned short* ga = A + (size_t)(m0 + w * 8 + rw) * 1024 + cu;
  const unsigned short* gb = Bt + (size_t)(n0 + w * 8 + rw) * 1024 + cu;
  unsigned short* la = As + (w * 8) * 64;        // wave-uniform LDS base
  unsigned short* lb = Bs + (w * 8) * 64;
  const int lr = lane & 15, lku = lane >> 4;     // frag row / k-unit base
  const int wr = w >> 1, wc = w & 1;
  const int xr = lr & 7;
  f32x4 acc[4][4] = {};
  for (int kt = 0; kt < 1024; kt += 64) {
#pragma unroll
    for (int g = 0; g < 4; ++g) {
      GLOAD16(ga + kt + (size_t)(g * 32) * 1024, la + g * 32 * 64);
      GLOAD16(gb + kt + (size_t)(g * 32) * 1024, lb + g * 32 * 64);
    }
    __syncthreads();
#pragma unroll
    for (int kk = 0; kk < 2; ++kk) {  // k-halves of 32
      const int un = (((kk * 4 + lku) ^ xr) * 8);  // swizzled 16B unit
      bf16x8 aF[4], bF[4];
#pragma unroll
      for (int i = 0; i < 4; ++i) {
        aF[i] = *reinterpret_cast<const bf16x8*>(&As[(wr * 64 + i * 16 + lr) * 64 + un]);
        bF[i] = *reinterpret_cast<const bf16x8*>(&Bs[(wc * 64 + i * 16 + lr) * 64 + un]);
      }
#pragma unroll
      for (int i = 0; i < 4; ++i)
#pragma unroll
        for (int j = 0; j < 4; ++j)
          acc[i][j] = __builtin_amdgcn_mfma_f32_16x16x32_bf16(aF[i], bF[j], acc[i][j], 0, 0, 0);
    }
    __syncthreads();
  }
  const int r0 = m0 + wr * 64 + ((lane >> 4) << 2);
  if constexpr (EPI == 0) {
    float* O = (float*)out0;
    const int c0 = n0 + wc * 64 + lr;
#pragma unroll
    for (int i = 0; i < 4; ++i)
#pragma unroll
      for (int j = 0; j < 4; ++j)
#pragma unroll
        for (int r = 0; r < 4; ++r)
          O[(size_t)(r0 + i * 16 + r) * 1024 + c0 + j * 16] = acc[i][j][r];
  } else {
    const int col = n0 + wc * 64;  // 64-aligned, 0..3008
    if (col < 2048) {
      // RoPE epilogue -> q_bf (out0) or k_bf (out1)
      unsigned short* O = (col < 1024) ? (unsigned short*)out0 : out1;
      const int cbase = col & 1023;
#pragma unroll
      for (int i = 0; i < 4; ++i)
#pragma unroll
        for (int jj = 0; jj < 2; ++jj) {
          const int d1 = jj * 16 + lr;  // 0..31; cos[d]==cos[d+32]
#pragma unroll
          for (int r = 0; r < 4; ++r) {
            const int row = r0 + i * 16 + r;
            const int l = row & 4095;
            const float cv = cosb[(size_t)l * 64 + d1];
            const float sv = sinb[(size_t)l * 64 + d1];
            const float v1 = acc[i][jj][r], v2 = acc[i][jj + 2][r];
            O[(size_t)row * 1024 + cbase + jj * 16 + lr] = f2bf(v1 * cv - v2 * sv);
            O[(size_t)row * 1024 + cbase + jj * 16 + lr + 32] = f2bf(v2 * cv + v1 * sv);
          }
        }
    } else {
      // dt-scale epilogue -> xv_bf (out2)
      unsigned short* O = out2;
      const int cbase = col - 2048;
      const int h = cbase >> 6;
#pragma unroll
      for (int i = 0; i < 4; ++i)
#pragma unroll
        for (int r = 0; r < 4; ++r) {
          const int row = r0 + i * 16 + r;
          const float dtv = dtb[(size_t)row * 16 + h];
#pragma unroll
          for (int j = 0; j < 4; ++j)
            O[(size_t)row * 1024 + cbase + j * 16 + lr] = f2bf(acc[i][j][r] * dtv);
        }
    }
  }
}

// ---------------- SSD pre-scan: chunk states (MFMA, bf16 out) ----------------
__global__ __launch_bounds__(256) void ssd_states_kernel(
    const unsigned short* __restrict__ Kb, const unsigned short* __restrict__ Xb,
    const float* __restrict__ dtb, const float* __restrict__ A_log,
    unsigned short* __restrict__ chunk_states, float* __restrict__ chunk_dec) {
  __shared__ unsigned short T1[64 * 72], T2[64 * 72];   // B, X row-major
  __shared__ unsigned short BtL[64 * 72], XdL[64 * 72]; // transposed (k = s)
  __shared__ float csL[64], decL[64];
  const int c = blockIdx.x, h = blockIdx.y, b = blockIdx.z;
  const int tid = threadIdx.x, lane = tid & 63, w = tid >> 6;
  const size_t gbase = ((size_t)(b * 4096 + c * 64)) * 1024 + h * 64;
  {
    const int s = tid >> 2, e0 = (tid & 3) * 16;
    const unsigned short* gk = Kb + gbase + (size_t)s * 1024 + e0;
    const unsigned short* gx = Xb + gbase + (size_t)s * 1024 + e0;
    *(u32x4*)&T1[s * 72 + e0] = *(const u32x4*)gk;
    *(u32x4*)&T1[s * 72 + e0 + 8] = *(const u32x4*)(gk + 8);
    *(u32x4*)&T2[s * 72 + e0] = *(const u32x4*)gx;
    *(u32x4*)&T2[s * 72 + e0 + 8] = *(const u32x4*)(gx + 8);
  }
  if (w == 0) {
    float a = -expf(A_log[h]) * dtb[((size_t)(b * 4096 + c * 64 + lane)) * 16 + h];
    float v = a;
#pragma unroll
    for (int d = 1; d < 64; d <<= 1) {
      float o = __shfl_up(v, d, 64);
      if (lane >= d) v += o;
    }
    const float tot = __shfl(v, 63, 64);
    csL[lane] = v;
    decL[lane] = expf(tot - v);
    if (lane == 0) chunk_dec[((size_t)(b * 16 + h)) * 64 + c] = expf(tot);
  }
  __syncthreads();
#pragma unroll
  for (int q = 0; q < 2; ++q) {  // transpose with dec fold-in
    const int p = lane;
    const int s0 = (q * 4 + w) * 8;
    u16x8 vb, vx;
#pragma unroll
    for (int j = 0; j < 8; ++j) {
      vb[j] = T1[(s0 + j) * 72 + p];
      vx[j] = f2bf(bf2f(T2[(s0 + j) * 72 + p]) * decL[s0 + j]);
    }
    *(u16x8*)&BtL[p * 72 + s0] = vb;
    *(u16x8*)&XdL[p * 72 + s0] = vx;
  }
  __syncthreads();
  const int lr = lane & 15, lk = (lane >> 4) * 8;
  f32x4 acc[4] = {};
#pragma unroll
  for (int kt = 0; kt < 64; kt += 32) {
    bf16x8 aF = *reinterpret_cast<const bf16x8*>(&XdL[(w * 16 + lr) * 72 + kt + lk]);
#pragma unroll
    for (int j = 0; j < 4; ++j) {
      bf16x8 bF = *reinterpret_cast<const bf16x8*>(&BtL[(j * 16 + lr) * 72 + kt + lk]);
      acc[j] = __builtin_amdgcn_mfma_f32_16x16x32_bf16(aF, bF, acc[j], 0, 0, 0);
    }
  }
  const size_t stb = ((size_t)((b * 64 + c) * 16 + h)) * 4096;
#pragma unroll
  for (int j = 0; j < 4; ++j)
#pragma unroll
    for (int r = 0; r < 4; ++r)
      chunk_states[stb + (size_t)(w * 16 + (lane >> 4) * 4 + r) * 64 + j * 16 + lr] =
          f2bf(acc[j][r]);
}

// ---------------- inter-chunk scan (prefetch depth 2) ----------------
__global__ __launch_bounds__(256) void scan_kernel(
    const unsigned short* __restrict__ chunk_states, const float* __restrict__ chunk_dec,
    unsigned short* __restrict__ inc_bf, float* __restrict__ state_out) {
  __shared__ float decs[64];
  const int g = blockIdx.x * 256 + threadIdx.x;
  const int n = g & 63, p = (g >> 6) & 63, h = (g >> 12) & 15, b = g >> 16;
  if (threadIdx.x < 64)
    decs[threadIdx.x] = chunk_dec[(size_t)((blockIdx.x * 256) >> 12 & 15) * 64 +
                                  (size_t)(blockIdx.x >> 8) * 1024 + threadIdx.x];
  __syncthreads();
  const size_t pn = (size_t)p * 64 + n;
  const size_t stride = (size_t)16 * 4096;
  const size_t base0 = ((size_t)(b * 64) * 16 + h) * 4096 + pn;
  float inc = 0.f;
  float cur0 = bf2f(chunk_states[base0]);
  float cur1 = bf2f(chunk_states[base0 + stride]);
  for (int c = 0; c < 64; ++c) {
    const size_t idx = base0 + (size_t)c * stride;
    inc_bf[idx] = f2bf(inc);
    float nxt = (c < 62) ? bf2f(chunk_states[idx + 2 * stride]) : 0.f;
    inc = decs[c] * inc + cur0;
    cur0 = cur1;
    cur1 = nxt;
  }
  state_out[((size_t)(b * 16 + h) * 64 + p) * 64 + n] = inc;
}

// ---------------- SSD post-scan: Y = Gm@X + (C.sde)@S^T (MFMA) ----------------
__global__ __launch_bounds__(256) void ssd_y_kernel(
    const unsigned short* __restrict__ Qb, const unsigned short* __restrict__ Kb,
    const unsigned short* __restrict__ Xb, const unsigned short* __restrict__ Sg,
    const float* __restrict__ dtb, const float* __restrict__ A_log,
    unsigned short* __restrict__ y_bf) {
  __shared__ unsigned short Cb[64 * 72], Bb[64 * 72];
  __shared__ unsigned short Xt[64 * 72], TG[64 * 72];  // TG: X rm, then Gm
  __shared__ float csL[64], sdeL[64];
  const int c = blockIdx.x, h = blockIdx.y, b = blockIdx.z;
  const int tid = threadIdx.x, lane = tid & 63, w = tid >> 6;
  const size_t gbase = ((size_t)(b * 4096 + c * 64)) * 1024 + h * 64;
  const size_t sbase = ((size_t)((b * 64 + c) * 16 + h)) * 4096;
  const unsigned short* gS = Sg + sbase;  // [p][n] bf16, L2-hot
  {
    const int s = tid >> 2, e0 = (tid & 3) * 16;
    const unsigned short* gq = Qb + gbase + (size_t)s * 1024 + e0;
    const unsigned short* gk = Kb + gbase + (size_t)s * 1024 + e0;
    const unsigned short* gx = Xb + gbase + (size_t)s * 1024 + e0;
    *(u32x4*)&Cb[s * 72 + e0] = *(const u32x4*)gq;
    *(u32x4*)&Cb[s * 72 + e0 + 8] = *(const u32x4*)(gq + 8);
    *(u32x4*)&Bb[s * 72 + e0] = *(const u32x4*)gk;
    *(u32x4*)&Bb[s * 72 + e0 + 8] = *(const u32x4*)(gk + 8);
    *(u32x4*)&TG[s * 72 + e0] = *(const u32x4*)gx;
    *(u32x4*)&TG[s * 72 + e0 + 8] = *(const u32x4*)(gx + 8);
  }
  if (w == 0) {
    float a = -expf(A_log[h]) * dtb[((size_t)(b * 4096 + c * 64 + lane)) * 16 + h];
    float v = a;
#pragma unroll
    for (int d = 1; d < 64; d <<= 1) {
      float o = __shfl_up(v, d, 64);
      if (lane >= d) v += o;
    }
    csL[lane] = v;
    sdeL[lane] = expf(v);
  }
  __syncthreads();
  const int lr = lane & 15, lk = (lane >> 4) * 8;
  // G = C @ B^T (contract n)
  f32x4 g[4] = {};
#pragma unroll
  for (int kt = 0; kt < 64; kt += 32) {
    bf16x8 aF = *reinterpret_cast<const bf16x8*>(&Cb[(w * 16 + lr) * 72 + kt + lk]);
#pragma unroll
    for (int j = 0; j < 4; ++j) {
      bf16x8 bF = *reinterpret_cast<const bf16x8*>(&Bb[(j * 16 + lr) * 72 + kt + lk]);
      g[j] = __builtin_amdgcn_mfma_f32_16x16x32_bf16(aF, bF, g[j], 0, 0, 0);
    }
  }
  // transpose X: TG -> Xt
#pragma unroll
  for (int q = 0; q < 2; ++q) {
    const int p = lane;
    const int s0 = (q * 4 + w) * 8;
    u16x8 vx;
#pragma unroll
    for (int j = 0; j < 8; ++j) vx[j] = TG[(s0 + j) * 72 + p];
    *(u16x8*)&Xt[p * 72 + s0] = vx;
  }
  __syncthreads();
  // Gm = (G o L) -> TG ;  Cb *= sde[l]
#pragma unroll
  for (int j = 0; j < 4; ++j)
#pragma unroll
    for (int r = 0; r < 4; ++r) {
      const int l = w * 16 + (lane >> 4) * 4 + r;
      const int s = j * 16 + lr;
      const float gm = (l >= s) ? g[j][r] * expf(csL[l] - csL[s]) : 0.f;
      TG[l * 72 + s] = f2bf(gm);
    }
  {
    const int rl = tid >> 2, e0 = (tid & 3) * 16;
    const float sde = sdeL[rl];
#pragma unroll
    for (int half = 0; half < 2; ++half) {
      u16x8 v = *(u16x8*)&Cb[rl * 72 + e0 + half * 8];
#pragma unroll
      for (int j = 0; j < 8; ++j) v[j] = f2bf(bf2f(v[j]) * sde);
      *(u16x8*)&Cb[rl * 72 + e0 + half * 8] = v;
    }
  }
  __syncthreads();
  // Y = Gm @ Xt^T + Csde @ S^T  (S fragments straight from global/L2)
  f32x4 acc[4] = {};
#pragma unroll
  for (int kt = 0; kt < 64; kt += 32) {
    bf16x8 aG = *reinterpret_cast<const bf16x8*>(&TG[(w * 16 + lr) * 72 + kt + lk]);
    bf16x8 aC = *reinterpret_cast<const bf16x8*>(&Cb[(w * 16 + lr) * 72 + kt + lk]);
#pragma unroll
    for (int j = 0; j < 4; ++j) {
      bf16x8 bX = *reinterpret_cast<const bf16x8*>(&Xt[(j * 16 + lr) * 72 + kt + lk]);
      bf16x8 bS = *reinterpret_cast<const bf16x8*>(gS + (size_t)(j * 16 + lr) * 64 + kt + lk);
      acc[j] = __builtin_amdgcn_mfma_f32_16x16x32_bf16(aG, bX, acc[j], 0, 0, 0);
      acc[j] = __builtin_amdgcn_mfma_f32_16x16x32_bf16(aC, bS, acc[j], 0, 0, 0);
    }
  }
  // scrambled store: row = b*4096 + h*256 + c*4 + (l>>4), col = (l&15)*64 + p
  const size_t orow = (size_t)b * 4096 + h * 256 + c * 4 + w;
#pragma unroll
  for (int j = 0; j < 4; ++j)
#pragma unroll
    for (int r = 0; r < 4; ++r) {
      const int li = (lane >> 4) * 4 + r;
      y_bf[orow * 1024 + li * 64 + j * 16 + lr] = f2bf(acc[j][r]);
    }
}

// ---------------------------------------------------------------------------
extern "C" void kernel_launch(void* const* d_in, const int* in_sizes, int n_in,
                              void* d_out, int out_size, void* d_ws, size_t ws_size,
                              hipStream_t stream) {
  (void)in_sizes; (void)n_in; (void)out_size; (void)ws_size;
  const float* x = (const float*)d_in[0];
  const float* cosb = (const float*)d_in[1];
  const float* sinb = (const float*)d_in[2];
  const float* wq = (const float*)d_in[3];
  const float* wk = (const float*)d_in[4];
  const float* wv = (const float*)d_in[5];
  const float* wo = (const float*)d_in[6];
  const float* A_log = (const float*)d_in[7];
  const float* wdt = (const float*)d_in[8];
  const float* bdt = (const float*)d_in[9];

  float* out_y = (float*)d_out;        // (2,4096,1024) f32
  float* out_state = out_y + 8388608;  // (2,16,64,64) f32

  const size_t MBB = 1048576;
  char* ws = (char*)d_ws;
  unsigned short* x_bf = (unsigned short*)(ws);              // 16MB, reused as y_bf
  unsigned short* w_t = (unsigned short*)(ws + 16 * MBB);    // 8MB (q,k,v,o transposed)
  unsigned short* q_bf = (unsigned short*)(ws + 24 * MBB);   // 16MB
  unsigned short* k_bf = (unsigned short*)(ws + 40 * MBB);   // 16MB
  unsigned short* xv_bf = (unsigned short*)(ws + 56 * MBB);  // 16MB
  float* dtb = (float*)(ws + 72 * MBB);                      // 0.5MB
  unsigned short* wdt_bf = (unsigned short*)(ws + 73 * MBB); // 32KB
  unsigned short* chunk_states = (unsigned short*)(ws + 74 * MBB);  // 16MB bf16
  float* chunk_dec = (float*)(ws + 90 * MBB);                // 8KB
  unsigned short* inc_bf = (unsigned short*)(ws + 91 * MBB); // 16MB

  prep_kernel<<<12352, 256, 0, stream>>>(x, x_bf, wdt, wdt_bf, wq, wk, wv, wo, w_t);
  dt_gemm_kernel<<<256, 128, 0, stream>>>(x_bf, wdt_bf, bdt, dtb);

  // fused QKV GEMM: N = 3072 (wq^T | wk^T | wv^T contiguous in w_t)
  gemm128_kernel<3><<<dim3(24, 64), 256, 0, stream>>>(
      x_bf, w_t, q_bf, k_bf, xv_bf, cosb, sinb, dtb);

  ssd_states_kernel<<<dim3(64, 16, 2), 256, 0, stream>>>(k_bf, xv_bf, dtb, A_log,
                                                         chunk_states, chunk_dec);
  scan_kernel<<<512, 256, 0, stream>>>(chunk_states, chunk_dec, inc_bf, out_state);
  ssd_y_kernel<<<dim3(64, 16, 2), 256, 0, stream>>>(q_bf, k_bf, xv_bf, inc_bf, dtb, A_log,
                                                    x_bf /*y_bf*/);

  gemm128_kernel<0><<<dim3(8, 64), 256, 0, stream>>>(
      x_bf /*y_bf*/, w_t + 3 * MBB, out_y, nullptr, nullptr, nullptr, nullptr, nullptr);
}